// Round 2
// baseline (489.207 us; speedup 1.0000x reference)
//
#include <hip/hip_runtime.h>
#include <hip/hip_bf16.h>

typedef __bf16 bf16x8 __attribute__((ext_vector_type(8)));
typedef float  floatx4 __attribute__((ext_vector_type(4)));
typedef float  f32x4   __attribute__((ext_vector_type(4)));

constexpr int B_SZ  = 1024;
constexpr int NB    = 1024;
constexpr int DIN   = 64;
constexpr int DOUT  = 64;
constexpr int M_TILE = 128;               // batch rows per loop iteration (whole block)
constexpr int HALVES = 2;                 // blocks per n  (grid = NB*HALVES = 2048)
constexpr int LDS_STRIDE = 72;            // bf16 elems per W row (pad 64 -> 72, keeps 16B align)

__global__ __launch_bounds__(256)
void block_linear_kernel(const float* __restrict__ x,
                         const float* __restrict__ W,
                         const float* __restrict__ bias,
                         float* __restrict__ out)
{
    __shared__ __bf16 sW[DOUT * LDS_STRIDE];   // 9216 B

    // ---- XCD-bijective swizzle: grid 2048, xcd = bid & 7 under round-robin.
    // Each XCD owns 128 consecutive n (W panel = 2 MiB, L2-resident) and both
    // halves of each n land on the same XCD.
    const int bid  = blockIdx.x;
    const int xcd  = bid & 7;
    const int j    = bid >> 3;               // 0..255 within XCD
    const int n    = xcd * (NB / 8) + (j >> 1);
    const int half = j & 1;

    const int tid  = threadIdx.x;
    const int wave = tid >> 6;
    const int lane = tid & 63;
    const int r    = lane & 15;              // row-in-tile for A, col for B/D
    const int q    = lane >> 4;              // quad

    // ---- stage W[n] (64x64 fp32, 16 KB) -> LDS bf16, ONCE per block ----
    {
        const float4* Wf4 = reinterpret_cast<const float4*>(W + (size_t)n * DOUT * DIN);
        #pragma unroll
        for (int i = 0; i < 4; ++i) {
            const int e  = i * 256 + tid;       // float4 index in 64x64 tile
            const float4 f = Wf4[e];
            const int o  = e >> 4;
            const int k0 = (e & 15) << 2;
            union { __bf16 h[4]; ushort4 u; } pk;
            pk.h[0] = (__bf16)f.x; pk.h[1] = (__bf16)f.y;
            pk.h[2] = (__bf16)f.z; pk.h[3] = (__bf16)f.w;
            *reinterpret_cast<ushort4*>(&sW[o * LDS_STRIDE + k0]) = pk.u;
        }
    }

    // ---- bias per lane, hoisted out of the loop ----
    float bv[4];
    #pragma unroll
    for (int ot = 0; ot < 4; ++ot) bv[ot] = bias[n * DOUT + ot * 16 + r];

    __syncthreads();

    // ---- B fragments from LDS -> registers, ONCE. LDS untouched afterwards,
    // so the m-loop has no barriers at all. B[n = lane&15][k = quad*8+j] ----
    bf16x8 bfrag[4][2];
    #pragma unroll
    for (int ot = 0; ot < 4; ++ot) {
        #pragma unroll
        for (int ks = 0; ks < 2; ++ks) {
            const int o = ot * 16 + r;
            bfrag[ot][ks] = *reinterpret_cast<const bf16x8*>(
                &sW[o * LDS_STRIDE + ks * 32 + q * 8]);
        }
    }

    const int row0 = half * (B_SZ / HALVES) + wave * 32;   // this wave's base row

    // ---- raw A-tile loads (nontemporal: x is streamed exactly once) ----
    auto load_raw = [&](int t, f32x4 (&raw)[2][2][2]) {
        #pragma unroll
        for (int mtile = 0; mtile < 2; ++mtile) {
            const size_t row = (size_t)(row0 + t * M_TILE + mtile * 16 + r);
            const float* pr  = x + (row * NB + n) * DIN + q * 8;
            #pragma unroll
            for (int ks = 0; ks < 2; ++ks) {
                const f32x4* p = reinterpret_cast<const f32x4*>(pr + ks * 32);
                raw[mtile][ks][0] = __builtin_nontemporal_load(p);
                raw[mtile][ks][1] = __builtin_nontemporal_load(p + 1);
            }
        }
    };

    // ---- convert -> MFMA -> bias -> nontemporal store ----
    auto compute_store = [&](int t, f32x4 (&raw)[2][2][2]) {
        bf16x8 afrag[2][2];
        #pragma unroll
        for (int mtile = 0; mtile < 2; ++mtile) {
            #pragma unroll
            for (int ks = 0; ks < 2; ++ks) {
                bf16x8 a;
                #pragma unroll
                for (int v = 0; v < 4; ++v) {
                    a[v]     = (__bf16)raw[mtile][ks][0][v];
                    a[4 + v] = (__bf16)raw[mtile][ks][1][v];
                }
                afrag[mtile][ks] = a;
            }
        }

        floatx4 acc[2][4];
        #pragma unroll
        for (int mtile = 0; mtile < 2; ++mtile)
            #pragma unroll
            for (int ot = 0; ot < 4; ++ot)
                acc[mtile][ot] = (floatx4){0.f, 0.f, 0.f, 0.f};

        #pragma unroll
        for (int mtile = 0; mtile < 2; ++mtile)
            #pragma unroll
            for (int ot = 0; ot < 4; ++ot)
                #pragma unroll
                for (int ks = 0; ks < 2; ++ks)
                    acc[mtile][ot] = __builtin_amdgcn_mfma_f32_16x16x32_bf16(
                        afrag[mtile][ks], bfrag[ot][ks], acc[mtile][ot], 0, 0, 0);

        // D: col = lane&15, row = quad*4 + reg  (verified layout)
        #pragma unroll
        for (int ot = 0; ot < 4; ++ot) {
            #pragma unroll
            for (int mtile = 0; mtile < 2; ++mtile) {
                #pragma unroll
                for (int reg = 0; reg < 4; ++reg) {
                    const size_t row = (size_t)(row0 + t * M_TILE + mtile * 16 + q * 4 + reg);
                    __builtin_nontemporal_store(
                        acc[mtile][ot][reg] + bv[ot],
                        &out[(row * NB + n) * DOUT + ot * 16 + r]);
                }
            }
        }
    };

    // ---- 2-deep register double-buffer over 4 m-tiles (all static indices) ----
    f32x4 rawA[2][2][2], rawB[2][2][2];
    load_raw(0, rawA);
    load_raw(1, rawB);
    compute_store(0, rawA);
    load_raw(2, rawA);
    compute_store(1, rawB);
    load_raw(3, rawB);
    compute_store(2, rawA);
    compute_store(3, rawB);
}

extern "C" void kernel_launch(void* const* d_in, const int* in_sizes, int n_in,
                              void* d_out, int out_size, void* d_ws, size_t ws_size,
                              hipStream_t stream) {
    const float* x  = (const float*)d_in[0];
    const float* W  = (const float*)d_in[1];
    const float* b  = (const float*)d_in[2];
    float* out      = (float*)d_out;

    dim3 grid(NB * HALVES);   // 2048
    dim3 block(256);
    hipLaunchKernelGGL(block_linear_kernel, grid, block, 0, stream, x, W, b, out);
}

// Round 3
// 455.533 us; speedup vs baseline: 1.0739x; 1.0739x over previous
//
#include <hip/hip_runtime.h>
#include <hip/hip_bf16.h>

typedef __bf16 bf16x8 __attribute__((ext_vector_type(8)));
typedef float  floatx4 __attribute__((ext_vector_type(4)));
typedef float  f32x4   __attribute__((ext_vector_type(4)));

constexpr int B_SZ = 1024, NB = 1024, DIN = 64, DOUT = 64;
constexpr int G    = 8;              // consecutive n per workgroup -> 2 KB contiguous x/out per row
constexpr int MB   = 128;            // batch rows per workgroup
constexpr int CH   = 16;             // rows per staged chunk (one 16-row MFMA m-tile)
constexpr int NCH  = MB / CH;        // 8
constexpr int XSTR = G * DIN + 8;    // 520 bf16 per chunk-row (+8 pad: r-stride = 4 banks)
constexpr int OSTR = G * DOUT + 4;   // 516 f32  per chunk-row (+4 pad)
constexpr int ROWF = NB * DIN;       // 65536 floats per batch row (same for out: NB*DOUT)

// raw barrier: order LDS ops across waves WITHOUT draining vmcnt
// (prefetch loads / nontemporal stores stay in flight across it)
__device__ inline void lds_barrier() {
    asm volatile("s_waitcnt lgkmcnt(0)" ::: "memory");
    __builtin_amdgcn_s_barrier();
}

__global__ __launch_bounds__(256)
void block_linear_kernel(const float* __restrict__ x,
                         const float* __restrict__ W,
                         const float* __restrict__ bias,
                         float* __restrict__ out)
{
    __shared__ __bf16 xb[CH * XSTR];   // 16640 B, single-buffered (dead after frag reads)
    __shared__ float  ob[CH * OSTR];   // 33024 B  -> 49.7 KB total

    // XCD swizzle: 1024 blocks, xcd = bid&7 under round-robin. Each XCD owns
    // 16 n-groups (2 MiB fp32 of W, L2-resident) x 8 row-tiles.
    const int bid = blockIdx.x;
    const int xcd = bid & 7;
    const int idx = bid >> 3;            // 0..127
    const int ng  = xcd * 16 + (idx >> 3);   // n-group 0..127
    const int rt  = idx & 7;                 // row-tile 0..7

    const int tid = threadIdx.x;
    const int w    = tid >> 6;
    const int lane = tid & 63;
    const int r    = lane & 15;          // A-row / B,D-col
    const int q    = lane >> 4;          // quad

    const size_t colbase = (size_t)ng * (G * DIN);   // float offset of n-slab in a row
    const int    row0    = rt * MB;

    // ---- W -> register B-fragments; each wave owns 2 n (64 VGPRs). L2-served. ----
    bf16x8 bfrag[2][4][2];
    float  bv[2][4];
    #pragma unroll
    for (int nl = 0; nl < 2; ++nl) {
        const int n_g = ng * G + w * 2 + nl;
        const float* wp = W + (size_t)n_g * DOUT * DIN;
        #pragma unroll
        for (int ot = 0; ot < 4; ++ot) {
            bv[nl][ot] = bias[n_g * DOUT + ot * 16 + r];
            #pragma unroll
            for (int ks = 0; ks < 2; ++ks) {
                const float* p = wp + (ot * 16 + r) * DIN + ks * 32 + q * 8;
                const f32x4 f0 = *reinterpret_cast<const f32x4*>(p);
                const f32x4 f1 = *reinterpret_cast<const f32x4*>(p + 4);
                bf16x8 b;
                #pragma unroll
                for (int v = 0; v < 4; ++v) { b[v] = (__bf16)f0[v]; b[4+v] = (__bf16)f1[v]; }
                bfrag[nl][ot][ks] = b;
            }
        }
    }

    // ---- staging: e = i*256+tid maps to (row = e>>7, 16B slot = e&127).
    // One wave instruction = 64 consecutive e = 1 KB fully dense global access. ----
    auto issue_loads = [&](int c, f32x4 (&raw)[8]) {
        #pragma unroll
        for (int i = 0; i < 8; ++i) {
            const int e = i * 256 + tid;
            const int row = e >> 7, c4 = e & 127;
            const size_t rg = (size_t)(row0 + c * CH + row);
            raw[i] = __builtin_nontemporal_load(
                reinterpret_cast<const f32x4*>(x + rg * ROWF + colbase + c4 * 4));
        }
    };
    auto write_xb = [&](f32x4 (&raw)[8]) {
        #pragma unroll
        for (int i = 0; i < 8; ++i) {
            const int e = i * 256 + tid;
            const int row = e >> 7, c4 = e & 127;
            union { __bf16 h[4]; ushort4 u; } pk;
            #pragma unroll
            for (int v = 0; v < 4; ++v) pk.h[v] = (__bf16)raw[i][v];
            *reinterpret_cast<ushort4*>(&xb[row * XSTR + c4 * 4]) = pk.u;
        }
    };

    f32x4 raw[8], nxt[8];
    issue_loads(0, raw);
    write_xb(raw);
    lds_barrier();                       // xb ready

    for (int c = 0; c < NCH; ++c) {
        if (c + 1 < NCH) issue_loads(c + 1, nxt);   // prefetch under compute

        // A fragments from LDS: A[m=r][k=q*8+j] for this wave's 2 n
        bf16x8 af[2][2];
        #pragma unroll
        for (int nl = 0; nl < 2; ++nl) {
            const int n_loc = w * 2 + nl;
            #pragma unroll
            for (int ks = 0; ks < 2; ++ks)
                af[nl][ks] = *reinterpret_cast<const bf16x8*>(
                    &xb[r * XSTR + n_loc * 64 + ks * 32 + q * 8]);
        }

        floatx4 acc[2][4];
        #pragma unroll
        for (int nl = 0; nl < 2; ++nl)
            #pragma unroll
            for (int ot = 0; ot < 4; ++ot)
                acc[nl][ot] = (floatx4){0.f, 0.f, 0.f, 0.f};

        #pragma unroll
        for (int nl = 0; nl < 2; ++nl)
            #pragma unroll
            for (int ot = 0; ot < 4; ++ot)
                #pragma unroll
                for (int ks = 0; ks < 2; ++ks)
                    acc[nl][ot] = __builtin_amdgcn_mfma_f32_16x16x32_bf16(
                        af[nl][ks], bfrag[nl][ot][ks], acc[nl][ot], 0, 0, 0);

        // D (col=r, row=q*4+reg) + bias -> ob tile
        #pragma unroll
        for (int nl = 0; nl < 2; ++nl) {
            const int n_loc = w * 2 + nl;
            #pragma unroll
            for (int ot = 0; ot < 4; ++ot)
                #pragma unroll
                for (int reg = 0; reg < 4; ++reg)
                    ob[(q * 4 + reg) * OSTR + n_loc * 64 + ot * 16 + r]
                        = acc[nl][ot][reg] + bv[nl][ot];
        }

        lds_barrier();                   // ob complete; xb reads done

        // ob -> global: dense 1 KB per wave instruction, 2 KB contiguous per row
        #pragma unroll
        for (int i = 0; i < 8; ++i) {
            const int e = i * 256 + tid;
            const int row = e >> 7, c4 = e & 127;
            const size_t rg = (size_t)(row0 + c * CH + row);
            const f32x4 v = *reinterpret_cast<const f32x4*>(&ob[row * OSTR + c4 * 4]);
            __builtin_nontemporal_store(
                v, reinterpret_cast<f32x4*>(out + rg * ROWF + colbase + c4 * 4));
        }

        if (c + 1 < NCH) write_xb(nxt);  // xb is dead past the frag reads -> overwrite in place

        lds_barrier();                   // ob drained + xb ready for c+1
    }
}

extern "C" void kernel_launch(void* const* d_in, const int* in_sizes, int n_in,
                              void* d_out, int out_size, void* d_ws, size_t ws_size,
                              hipStream_t stream) {
    const float* x  = (const float*)d_in[0];
    const float* W  = (const float*)d_in[1];
    const float* b  = (const float*)d_in[2];
    float* out      = (float*)d_out;

    dim3 grid((NB / G) * (B_SZ / MB));   // 128 * 8 = 1024
    dim3 block(256);
    hipLaunchKernelGGL(block_linear_kernel, grid, block, 0, stream, x, W, b, out);
}